// Round 7
// baseline (150.642 us; speedup 1.0000x reference)
//
#include <hip/hip_runtime.h>
#include <math.h>

#define BATCH 64
#define HH 512
#define WW 512
#define KRAD 15
#define KSZ 31
#define NTOT ((size_t)BATCH * HH * WW)
#define TILE_Y 32
#define NCHUNK (HH / TILE_Y)            // 16
#define NBLK (BATCH * NCHUNK)           // 1024 blocks
#define HROWS (TILE_Y + 2 * KRAD)       // 62 LDS rows
#define HALF_Y (TILE_Y / 2)             // 16 rows per stage-2 thread

typedef _Float16 h8 __attribute__((ext_vector_type(8)));
typedef _Float16 h2 __attribute__((ext_vector_type(2)));
typedef float    f2 __attribute__((ext_vector_type(2)));

// ---------------------------------------------------------------------------
// H-first strip (wave shuffle-scan -> fp16 LDS) + V running sum + fused loss.
// 1024-thread blocks (16 waves), 62 KB LDS -> 2 blocks/CU, 32 waves.
// Stage 2: 512 active threads, each 2 adjacent columns x 16 rows:
//   packed fp16x2 LDS reads + float2 global loads (half the instr count).
// ---------------------------------------------------------------------------
__global__ __launch_bounds__(1024, 8) void mega_kernel(const float* __restrict__ logits,
                                                       const float* __restrict__ targ,
                                                       float* __restrict__ pbuf) {
    __shared__ _Float16 Hlds[HROWS * WW];   // 62 KB

    const int b     = blockIdx.x >> 4;          // batch
    const int chunk = blockIdx.x & (NCHUNK - 1);
    const int y0    = chunk * TILE_Y;

    const int wave = threadIdx.x >> 6;          // 0..15
    const int lane = threadIdx.x & 63;

    // ---- Stage 1: H rows [y0-15, y0+46] -> LDS (fp16), 4 rows per wave ----
#pragma unroll
    for (int i = 0; i < 4; ++i) {
        const int r = i * 16 + wave;            // 0..63
        if (r >= HROWS) continue;               // wave-uniform
        const int y_abs = y0 - KRAD + r;

        h8 hv = {};
        if (y_abs >= 0 && y_abs < HH) {
            const float4* rp = (const float4*)(targ + ((size_t)b * HH + y_abs) * WW);
            float4 a  = rp[2 * lane];
            float4 b4 = rp[2 * lane + 1];
            float v[8] = {a.x, a.y, a.z, a.w, b4.x, b4.y, b4.z, b4.w};

            float T = 0.0f;
            float P[8];
#pragma unroll
            for (int j = 0; j < 8; ++j) { T += v[j]; P[j] = T; }

            float incl = T;
#pragma unroll
            for (int d = 1; d < 64; d <<= 1) {
                float n = __shfl_up(incl, d, 64);
                if (lane >= d) incl += n;
            }
            const float excl = incl - T;
            const float tot  = __shfl(incl, 63, 64);
#pragma unroll
            for (int j = 0; j < 8; ++j) P[j] += excl;

#pragma unroll
            for (int j = 0; j < 8; ++j) {
                const int q   = j + 15;             // 15..22 (compile-time)
                const int seg = lane + (q >> 3);
                float hi_sh = __shfl(P[q & 7], seg > 63 ? 63 : seg, 64);
                float hi    = (seg > 63) ? tot : hi_sh;
                float lo_sh = __shfl(P[j], lane >= 2 ? lane - 2 : 0, 64);
                float lo    = (lane >= 2) ? lo_sh : 0.0f;
                hv[j] = (_Float16)(hi - lo);
            }
        }
        *(h8*)&Hlds[r * WW + lane * 8] = hv;    // 16B aligned, contiguous
    }
    __syncthreads();

    // ---- Stage 2: threads 0..511: 2 adjacent columns x 16 rows each ----
    float a_wbce = 0.0f, a_int = 0.0f, a_tot = 0.0f;

    if (threadIdx.x < 512) {
        const int pr   = threadIdx.x & 255;     // column pair 0..255
        const int x0   = pr * 2;                // even column
        const int half = threadIdx.x >> 8;      // 0 or 1
        const int l0   = half * HALF_Y;         // local starting row

        const size_t base = ((size_t)b * HH + y0 + l0) * WW + x0;
        const f2* Tp = (const f2*)(targ   + base);   // row stride: 256 f2
        const f2* Lp = (const f2*)(logits + base);

        float vs0 = 0.0f, vs1 = 0.0f;
#pragma unroll
        for (int r = 0; r < KSZ; ++r) {
            h2 hv = *(const h2*)&Hlds[(l0 + r) * WW + x0];
            vs0 += (float)hv.x; vs1 += (float)hv.y;
        }

        const float inv_ksq = 1.0f / (float)(KSZ * KSZ);

#pragma unroll 4
        for (int j = 0; j < HALF_Y; ++j) {
            const f2 t2 = Tp[(size_t)j * (WW / 2)];
            const f2 L2 = __builtin_nontemporal_load(Lp + (size_t)j * (WW / 2));

#pragma unroll
            for (int c = 0; c < 2; ++c) {
                const float s = (c == 0 ? vs0 : vs1) * inv_ksq;
                const float t = t2[c];
                const float L = L2[c];

                const float weit = 1.0f + 5.0f * fabsf(s - t);
                const float e  = __expf(-fabsf(L));
                const float r  = __builtin_amdgcn_rcpf(1.0f + e);
                const float lg = __logf(1.0f + e);          // softplus(-|L|)
                const float sp  = fmaxf(L, 0.0f) + lg;      // softplus(L)
                const float bce = sp - t * L;
                const float p   = (L >= 0.0f) ? r : e * r;  // sigmoid(L)

                a_wbce += weit * bce;
                a_int  += p * t * weit;
                a_tot  += (p + t) * weit;
            }

            if (j < HALF_Y - 1) {
                const int l = l0 + j;
                h2 ha = *(const h2*)&Hlds[(l + KSZ) * WW + x0];
                h2 hb = *(const h2*)&Hlds[l * WW + x0];
                vs0 += (float)ha.x - (float)hb.x;
                vs1 += (float)ha.y - (float)hb.y;
            }
        }
    }

    // ---- Block reduction: wave shuffle + LDS + plain per-block stores ----
#pragma unroll
    for (int off = 32; off > 0; off >>= 1) {
        a_wbce += __shfl_down(a_wbce, off, 64);
        a_int  += __shfl_down(a_int,  off, 64);
        a_tot  += __shfl_down(a_tot,  off, 64);
    }

    __shared__ float red[3][16];
    if (lane == 0) {
        red[0][wave] = a_wbce; red[1][wave] = a_int; red[2][wave] = a_tot;
    }
    __syncthreads();
    if (threadIdx.x == 0) {
        float w = 0.0f, i2 = 0.0f, t2 = 0.0f;
#pragma unroll
        for (int k = 0; k < 16; ++k) { w += red[0][k]; i2 += red[1][k]; t2 += red[2][k]; }
        pbuf[blockIdx.x]            = w;
        pbuf[NBLK + blockIdx.x]     = i2;
        pbuf[2 * NBLK + blockIdx.x] = t2;
    }
}

// ---------------------------------------------------------------------------
// Finalize: reduce 1024 partials per quantity (double accum) + scalar.
// ---------------------------------------------------------------------------
__global__ __launch_bounds__(256) void finalize_kernel(const float* __restrict__ pbuf,
                                                       float* __restrict__ out) {
    const int tidx = threadIdx.x;
    double w = 0.0, i2 = 0.0, t2 = 0.0;
    for (int k = tidx; k < NBLK; k += 256) {
        w  += (double)pbuf[k];
        i2 += (double)pbuf[NBLK + k];
        t2 += (double)pbuf[2 * NBLK + k];
    }
#pragma unroll
    for (int off = 32; off > 0; off >>= 1) {
        w  += __shfl_down(w,  off, 64);
        i2 += __shfl_down(i2, off, 64);
        t2 += __shfl_down(t2, off, 64);
    }
    __shared__ double red[3][4];
    const int wave = tidx >> 6;
    if ((tidx & 63) == 0) { red[0][wave] = w; red[1][wave] = i2; red[2][wave] = t2; }
    __syncthreads();
    if (tidx == 0) {
        double ws = 0.0, is = 0.0, ts = 0.0;
        for (int k = 0; k < 4; ++k) { ws += red[0][k]; is += red[1][k]; ts += red[2][k]; }
        const double wbce   = ws / (double)NTOT;
        const double union_ = ts - is;
        const double wiou   = 1.0 - (is + 1.0) / (union_ + 1.0);
        out[0] = (float)(wbce + wiou);
    }
}

extern "C" void kernel_launch(void* const* d_in, const int* in_sizes, int n_in,
                              void* d_out, int out_size, void* d_ws, size_t ws_size,
                              hipStream_t stream) {
    const float* logits = (const float*)d_in[0];
    const float* targ   = (const float*)d_in[1];
    float* out          = (float*)d_out;
    float* pbuf         = (float*)d_ws;     // 3*NBLK floats (12 KB)

    mega_kernel<<<NBLK, 1024, 0, stream>>>(logits, targ, pbuf);
    finalize_kernel<<<1, 256, 0, stream>>>(pbuf, out);
}